// Round 2
// baseline (383.800 us; speedup 1.0000x reference)
//
#include <hip/hip_runtime.h>
#include <hip/hip_bf16.h>
#include <math.h>

// ---------------- types ----------------
typedef __bf16 bf16_t;
typedef __bf16 bf16x4 __attribute__((ext_vector_type(4)));
typedef __bf16 bf16x8 __attribute__((ext_vector_type(8)));
typedef float  f32x4  __attribute__((ext_vector_type(4)));

#define T_TOK 4096
#define H_DIM 1024
#define E_NUM 16
#define F_DIM 4096
#define CH_MAX 16   // max 256-row chunks per expert

// ---------------- workspace layout (bytes) ----------------
#define WS_E0     0            // int[4096]
#define WS_E1     16384        // int[4096]
#define WS_W0     32768        // float[4096]
#define WS_W1     49152        // float[4096]
#define WS_COUNTS 65536        // int[16]
#define WS_SUMW   65664        // float[16]
#define WS_XOFF   65792        // int[16]
#define WS_LIDX   131072       // int[16][4096]
#define WS_LW     393216       // float[16][4096]
#define WS_GPART  655360       // float[16][16][4096]  (4 MB)
#define WS_G      4849664      // float[16][4096]
#define WS_P2     5111808      // float[512][1024]     (2 MB)
#define WS_XE     7208960      // bf16[12288][1024]    (24 MB), swizzle-permuted
// total ~32.4 MB

#define AS_GLOBAL(p) ((const __attribute__((address_space(1))) void*)(p))
#define AS_LDS(p)    ((__attribute__((address_space(3))) void*)(p))

// ---------------- kernel 1: routing (scores + top2 + softmax) ----------------
__global__ __launch_bounds__(64) void k_route(const float* __restrict__ x,
    const float* __restrict__ Wg, const float* __restrict__ bg,
    int* __restrict__ e0, int* __restrict__ e1,
    float* __restrict__ w0, float* __restrict__ w1)
{
    const int t = blockIdx.x;
    const int lane = threadIdx.x;
    const float* xr = x + (size_t)t * H_DIM;

    float s[E_NUM];
#pragma unroll
    for (int e = 0; e < E_NUM; ++e) s[e] = 0.f;

#pragma unroll
    for (int i = 0; i < 16; ++i) {
        const int h = i * 64 + lane;
        const float xv = xr[h];
        const float4* wr = (const float4*)(Wg + (size_t)h * E_NUM);
        float4 q0 = wr[0], q1 = wr[1], q2 = wr[2], q3 = wr[3];
        s[0] += xv*q0.x;  s[1] += xv*q0.y;  s[2] += xv*q0.z;  s[3] += xv*q0.w;
        s[4] += xv*q1.x;  s[5] += xv*q1.y;  s[6] += xv*q1.z;  s[7] += xv*q1.w;
        s[8] += xv*q2.x;  s[9] += xv*q2.y;  s[10]+= xv*q2.z;  s[11]+= xv*q2.w;
        s[12]+= xv*q3.x;  s[13]+= xv*q3.y;  s[14]+= xv*q3.z;  s[15]+= xv*q3.w;
    }
#pragma unroll
    for (int off = 32; off >= 1; off >>= 1) {
#pragma unroll
        for (int e = 0; e < E_NUM; ++e) s[e] += __shfl_xor(s[e], off);
    }
    if (lane == 0) {
#pragma unroll
        for (int e = 0; e < E_NUM; ++e) s[e] += bg[e];
        float b1v = -3e38f; int i1 = 0;
#pragma unroll
        for (int e = 0; e < E_NUM; ++e) { if (s[e] > b1v) { b1v = s[e]; i1 = e; } }
        float b2v = -3e38f; int i2 = 0;
#pragma unroll
        for (int e = 0; e < E_NUM; ++e) { if (e != i1 && s[e] > b2v) { b2v = s[e]; i2 = e; } }
        const float ex  = expf(b2v - b1v);
        const float inv = 1.f / (1.f + ex);
        e0[t] = i1; e1[t] = i2;
        w0[t] = inv; w1[t] = ex * inv;
    }
}

// ---------------- kernel 2: per-expert token lists ----------------
__global__ __launch_bounds__(64) void k_lists(const int* __restrict__ e0, const int* __restrict__ e1,
    const float* __restrict__ w0, const float* __restrict__ w1,
    int* __restrict__ lidx, float* __restrict__ lw,
    int* __restrict__ counts, float* __restrict__ sumw)
{
    const int e = blockIdx.x;
    const int lane = threadIdx.x;
    int cnt = 0; float sw = 0.f;
    for (int base = 0; base < T_TOK; base += 64) {
        const int t = base + lane;
        const bool m0 = (e0[t] == e);
        const bool m1 = (e1[t] == e);
        const bool m  = m0 | m1;
        const unsigned long long bal = __ballot(m);
        const int pos = cnt + __popcll(bal & ((1ull << lane) - 1ull));
        if (m) {
            const float w = m0 ? w0[t] : w1[t];
            lidx[e * T_TOK + pos] = t;
            lw[e * T_TOK + pos]   = w;
            sw += w;
        }
        cnt += __popcll(bal);
    }
#pragma unroll
    for (int off = 32; off >= 1; off >>= 1) sw += __shfl_xor(sw, off);
    if (lane == 0) { counts[e] = cnt; sumw[e] = sw; }
}

// ---------------- kernel 3: exclusive scan of padded counts ----------------
__global__ void k_scan(const int* __restrict__ counts, int* __restrict__ xoff) {
    if (threadIdx.x == 0) {
        int o = 0;
        for (int e = 0; e < E_NUM; ++e) { xoff[e] = o; o += (counts[e] + 255) & ~255; }
    }
}

// ---------------- kernel 4: gather + f32->bf16 + chunk-swizzle into Xe ----------------
// Xe row layout: per 64-elem window, 16B chunk s holds logical chunk s ^ (row&7).
// This makes k_expert's global_load_lds source fully LINEAR while LDS reads
// apply the XOR swizzle -> conflict-free ds_read_b128.
__global__ __launch_bounds__(256) void k_gather(const float* __restrict__ x,
    const int* __restrict__ lidx, const int* __restrict__ counts,
    const int* __restrict__ xoff, bf16_t* __restrict__ Xe)
{
    const int chunk = blockIdx.x, e = blockIdx.y;
    const int cnt = counts[e];
    const int start = chunk * 256;
    if (chunk && start >= cnt) return;
    const int tid = threadIdx.x;
    const size_t rbase = (size_t)xoff[e] + start;

    for (int it = 0; it < 128; ++it) {
        const int task = it * 256 + tid;
        const int rl   = task >> 7;      // 0..255 local row
        const int sc   = task & 127;     // storage chunk within row
        const int row  = start + rl;
        bf16x8 v8 = {};
        if (row < cnt) {
            const int tok = lidx[e * T_TOK + row];
            const int l   = (sc & 7) ^ (rl & 7);
            const int k   = (sc >> 3) * 64 + l * 8;
            const float4 a = *(const float4*)(x + (size_t)tok * H_DIM + k);
            const float4 b = *(const float4*)(x + (size_t)tok * H_DIM + k + 4);
            v8[0]=(bf16_t)a.x; v8[1]=(bf16_t)a.y; v8[2]=(bf16_t)a.z; v8[3]=(bf16_t)a.w;
            v8[4]=(bf16_t)b.x; v8[5]=(bf16_t)b.y; v8[6]=(bf16_t)b.z; v8[7]=(bf16_t)b.w;
        }
        *(bf16x8*)(Xe + (rbase + rl) * H_DIM + sc * 8) = v8;
    }
}

// ---------------- kernel 5: expert GEMM (bf16 MFMA) + gelu + weighted reduce ----------------
// grid: (F/64, CH_MAX, E). block 256 = 4 waves; wave tile 64 tok x 64 f; BK=64.
// A: global_load_lds dwordx4 from pre-swizzled Xe (linear). B: reg-staged f32->bf16
// transpose into padded [64][72] LDS. acc 4x4 f32x4 per wave.
__global__ __launch_bounds__(256, 2) void k_expert(
    const float* __restrict__ W1, const float* __restrict__ b1,
    const bf16_t* __restrict__ Xe, const float* __restrict__ lw,
    const int* __restrict__ counts, const int* __restrict__ xoff,
    float* __restrict__ gpart)
{
    const int ftile = blockIdx.x;   // 0..63
    const int chunk = blockIdx.y;   // 0..15
    const int e     = blockIdx.z;   // 0..15
    const int cnt   = counts[e];
    const int start = chunk * 256;
    if (chunk && start >= cnt) return;

    __shared__ __align__(16) bf16_t Alds[256 * 64];   // 32 KB, swizzled chunks
    __shared__ __align__(16) bf16_t Blds[64 * 72];    // 9 KB, padded rows (72 elems)
    __shared__ float w_s[256];
    __shared__ float b1_s[64];
    __shared__ float gred[4][64];

    const int tid  = threadIdx.x;
    const int lane = tid & 63;
    const int wid  = tid >> 6;      // wave id = M-group = B k-quad
    const int lr   = lane & 15;
    const int lg   = lane >> 4;

    {
        const int r = start + tid;
        w_s[tid] = (r < cnt) ? lw[e * T_TOK + r] : 0.f;
        if (tid < 64) b1_s[tid] = b1[(size_t)e * F_DIM + ftile * 64 + tid];
    }

    f32x4 acc[4][4];
#pragma unroll
    for (int i = 0; i < 4; ++i)
#pragma unroll
        for (int j = 0; j < 4; ++j)
#pragma unroll
            for (int q = 0; q < 4; ++q) acc[i][j][q] = 0.f;

    const bf16_t* Asrc = Xe + ((size_t)xoff[e] + start) * H_DIM;
    // B source: this wave's k-quad (16 k rows), lane's f column
    const float* W1p = W1 + (size_t)e * H_DIM * F_DIM + (size_t)ftile * 64 + lane;

    for (int k0 = 0; k0 < H_DIM; k0 += 64) {
        // ---- stage A: 8 x global_load_lds dwordx4 per thread's wave slot (linear) ----
#pragma unroll
        for (int p = 0; p < 8; ++p) {
            const int seg = wid * 8 + p;             // 0..31 (1KB LDS segment)
            const int r   = seg * 8 + (lane >> 3);   // 0..255
            const int c   = lane & 7;                // storage chunk
            const bf16_t* src = Asrc + (size_t)r * H_DIM + k0 + c * 8;
            __builtin_amdgcn_global_load_lds(AS_GLOBAL(src),
                AS_LDS((char*)Alds + seg * 1024), 16, 0, 0);
        }
        // ---- stage B: 16 coalesced dword loads (k-rows), cvt, 2 x ds_write_b128 ----
        {
            const float* wp = W1p + (size_t)(k0 + wid * 16) * F_DIM;
            float bv[16];
#pragma unroll
            for (int j = 0; j < 16; ++j) bv[j] = wp[(size_t)j * F_DIM];
            bf16x8 pk0, pk1;
#pragma unroll
            for (int q = 0; q < 8; ++q) { pk0[q] = (bf16_t)bv[q]; pk1[q] = (bf16_t)bv[8 + q]; }
            bf16_t* bdst = &Blds[lane * 72 + wid * 16];
            *(bf16x8*)bdst       = pk0;
            *(bf16x8*)(bdst + 8) = pk1;
        }
        __syncthreads();

        // ---- MFMA: 2 k-halves x 4 mf x 4 nf ----
#pragma unroll
        for (int kh = 0; kh < 2; ++kh) {
            bf16x8 af[4], bfr[4];
#pragma unroll
            for (int mf = 0; mf < 4; ++mf) {
                const int r = wid * 64 + mf * 16 + lr;
                const int eoff = (kh * 32 + lg * 8) ^ ((r & 7) * 8);  // swizzled elem offset
                af[mf] = *(const bf16x8*)&Alds[r * 64 + eoff];
            }
#pragma unroll
            for (int nf = 0; nf < 4; ++nf)
                bfr[nf] = *(const bf16x8*)&Blds[(nf * 16 + lr) * 72 + kh * 32 + lg * 8];
#pragma unroll
            for (int mf = 0; mf < 4; ++mf)
#pragma unroll
                for (int nf = 0; nf < 4; ++nf)
                    acc[mf][nf] = __builtin_amdgcn_mfma_f32_16x16x32_bf16(af[mf], bfr[nf], acc[mf][nf], 0, 0, 0);
        }
        __syncthreads();
    }

    // ---- epilogue: exact gelu + weighted token-reduce ----
    float gcol[4] = {0.f, 0.f, 0.f, 0.f};
#pragma unroll
    for (int nf = 0; nf < 4; ++nf) {
        const float bb = b1_s[nf * 16 + lr];
#pragma unroll
        for (int mf = 0; mf < 4; ++mf) {
#pragma unroll
            for (int i = 0; i < 4; ++i) {
                const int row = wid * 64 + mf * 16 + lg * 4 + i;  // C/D: col=lane&15, row=(lane>>4)*4+i
                const float h  = acc[mf][nf][i] + bb;
                const float gl = 0.5f * h * (1.f + erff(h * 0.70710678118654752f));
                gcol[nf] += w_s[row] * gl;
            }
        }
    }
#pragma unroll
    for (int nf = 0; nf < 4; ++nf) {
        gcol[nf] += __shfl_xor(gcol[nf], 16);
        gcol[nf] += __shfl_xor(gcol[nf], 32);
    }
    if (lane < 16) {
#pragma unroll
        for (int nf = 0; nf < 4; ++nf) gred[wid][nf * 16 + lane] = gcol[nf];
    }
    __syncthreads();
    if (tid < 64) {
        const float sum = gred[0][tid] + gred[1][tid] + gred[2][tid] + gred[3][tid];
        gpart[(size_t)(e * CH_MAX + chunk) * F_DIM + ftile * 64 + tid] = sum;
    }
}

// ---------------- kernel 6: reduce chunk partials -> g[e][F] ----------------
__global__ __launch_bounds__(256) void k_redg(const float* __restrict__ gpart,
    const int* __restrict__ counts, float* __restrict__ g)
{
    const int e = blockIdx.y;
    const int f = blockIdx.x * 256 + threadIdx.x;
    const int nch = (counts[e] + 255) >> 8;
    float s = 0.f;
    for (int c = 0; c < nch; ++c)
        s += gpart[(size_t)(e * CH_MAX + c) * F_DIM + f];
    g[(size_t)e * F_DIM + f] = s;
}

// ---------------- kernel 7: W2 GEMV partials ----------------
__global__ __launch_bounds__(256) void k_out1(const float* __restrict__ g,
    const float* __restrict__ W2, float* __restrict__ p2)
{
    const int fc = blockIdx.x;
    const int e  = blockIdx.y;
    const int tid = threadIdx.x;
    __shared__ float gs[128];
    if (tid < 128) gs[tid] = g[(size_t)e * F_DIM + fc * 128 + tid];
    __syncthreads();
    const float* W2p = W2 + (size_t)e * F_DIM * H_DIM + (size_t)fc * 128 * H_DIM;
    float ax = 0.f, ay = 0.f, az = 0.f, aw = 0.f;
#pragma unroll 4
    for (int f = 0; f < 128; ++f) {
        const float gv = gs[f];
        const float4 wv = *(const float4*)(W2p + (size_t)f * H_DIM + tid * 4);
        ax += gv * wv.x; ay += gv * wv.y; az += gv * wv.z; aw += gv * wv.w;
    }
    float4 st; st.x = ax; st.y = ay; st.z = az; st.w = aw;
    *(float4*)(p2 + (size_t)(e * 32 + fc) * H_DIM + tid * 4) = st;
}

// ---------------- kernel 8: final reduce + bias + normalize ----------------
__global__ __launch_bounds__(256) void k_out2(const float* __restrict__ p2,
    const float* __restrict__ sumw, const float* __restrict__ b2, float* __restrict__ out)
{
    const int tid = threadIdx.x;
    const int hh  = tid & 31;
    const int seg = tid >> 5;
    const int h   = blockIdx.x * 32 + hh;
    float s = 0.f;
    for (int j = 0; j < 64; ++j)
        s += p2[(size_t)(seg * 64 + j) * H_DIM + h];
    __shared__ float red[8][33];
    red[seg][hh] = s;
    __syncthreads();
    if (tid < 32) {
        const int h2 = blockIdx.x * 32 + tid;
        float tot = 0.f;
#pragma unroll
        for (int q = 0; q < 8; ++q) tot += red[q][tid];
        float tw = 0.f, bias = 0.f;
#pragma unroll
        for (int e = 0; e < E_NUM; ++e) { tw += sumw[e]; bias += sumw[e] * b2[e * H_DIM + h2]; }
        out[h2] = (tot + bias) / tw;
    }
}

// ---------------- launch ----------------
extern "C" void kernel_launch(void* const* d_in, const int* in_sizes, int n_in,
                              void* d_out, int out_size, void* d_ws, size_t ws_size,
                              hipStream_t stream) {
    const float* x  = (const float*)d_in[0];
    const float* Wg = (const float*)d_in[1];
    const float* bg = (const float*)d_in[2];
    const float* W1 = (const float*)d_in[3];
    const float* b1 = (const float*)d_in[4];
    const float* W2 = (const float*)d_in[5];
    const float* b2 = (const float*)d_in[6];
    float* out = (float*)d_out;

    char* ws = (char*)d_ws;
    int*    e0     = (int*)(ws + WS_E0);
    int*    e1     = (int*)(ws + WS_E1);
    float*  w0     = (float*)(ws + WS_W0);
    float*  w1     = (float*)(ws + WS_W1);
    int*    counts = (int*)(ws + WS_COUNTS);
    float*  sumw   = (float*)(ws + WS_SUMW);
    int*    xoff   = (int*)(ws + WS_XOFF);
    int*    lidx   = (int*)(ws + WS_LIDX);
    float*  lw     = (float*)(ws + WS_LW);
    float*  gpart  = (float*)(ws + WS_GPART);
    float*  g      = (float*)(ws + WS_G);
    float*  p2     = (float*)(ws + WS_P2);
    bf16_t* Xe     = (bf16_t*)(ws + WS_XE);

    k_route<<<T_TOK, 64, 0, stream>>>(x, Wg, bg, e0, e1, w0, w1);
    k_lists<<<E_NUM, 64, 0, stream>>>(e0, e1, w0, w1, lidx, lw, counts, sumw);
    k_scan<<<1, 64, 0, stream>>>(counts, xoff);
    k_gather<<<dim3(CH_MAX, E_NUM), 256, 0, stream>>>(x, lidx, counts, xoff, Xe);
    k_expert<<<dim3(F_DIM / 64, CH_MAX, E_NUM), 256, 0, stream>>>(W1, b1, Xe, lw, counts, xoff, gpart);
    k_redg<<<dim3(F_DIM / 256, E_NUM), 256, 0, stream>>>(gpart, counts, g);
    k_out1<<<dim3(32, E_NUM), 256, 0, stream>>>(g, W2, p2);
    k_out2<<<32, 256, 0, stream>>>(p2, sumw, b2, out);
}

// Round 3
// 313.472 us; speedup vs baseline: 1.2244x; 1.2244x over previous
//
#include <hip/hip_runtime.h>
#include <hip/hip_bf16.h>
#include <math.h>

// ---------------- types ----------------
typedef __bf16 bf16_t;
typedef __bf16 bf16x4 __attribute__((ext_vector_type(4)));
typedef __bf16 bf16x8 __attribute__((ext_vector_type(8)));
typedef float  f32x4  __attribute__((ext_vector_type(4)));

#define T_TOK 4096
#define H_DIM 1024
#define E_NUM 16
#define F_DIM 4096
#define CH_ROWS 128   // tokens per chunk-block
#define CH_MAX  32    // max chunks per expert

// ---------------- workspace layout (bytes) ----------------
#define WS_E0     0            // int[4096]
#define WS_E1     16384        // int[4096]
#define WS_W0     32768        // float[4096]
#define WS_W1     49152        // float[4096]
#define WS_COUNTS 65536        // int[16]
#define WS_SUMW   65664        // float[16]
#define WS_XOFF   65792        // int[16]
#define WS_LIDX   131072       // int[16][4096]
#define WS_LW     393216       // float[16][4096]
#define WS_GPART  655360       // float[16][32][4096]  (8 MB)
#define WS_P2     655360       // float[512][1024] (2 MB) ALIASES gpart (dead after k_redg)
#define WS_G      9043968      // float[16][4096]
#define WS_XE     9306112      // bf16[10240][1024]  (20 MB), swizzle-permuted
// total: 30,277,632 bytes (< 32.4 MB known-good)

#define AS_GLOBAL(p) ((const __attribute__((address_space(1))) void*)(p))
#define AS_LDS(p)    ((__attribute__((address_space(3))) void*)(p))

// ---------------- kernel 1: routing (scores + top2 + softmax) ----------------
__global__ __launch_bounds__(64) void k_route(const float* __restrict__ x,
    const float* __restrict__ Wg, const float* __restrict__ bg,
    int* __restrict__ e0, int* __restrict__ e1,
    float* __restrict__ w0, float* __restrict__ w1)
{
    const int t = blockIdx.x;
    const int lane = threadIdx.x;
    const float* xr = x + (size_t)t * H_DIM;

    float s[E_NUM];
#pragma unroll
    for (int e = 0; e < E_NUM; ++e) s[e] = 0.f;

#pragma unroll
    for (int i = 0; i < 16; ++i) {
        const int h = i * 64 + lane;
        const float xv = xr[h];
        const float4* wr = (const float4*)(Wg + (size_t)h * E_NUM);
        float4 q0 = wr[0], q1 = wr[1], q2 = wr[2], q3 = wr[3];
        s[0] += xv*q0.x;  s[1] += xv*q0.y;  s[2] += xv*q0.z;  s[3] += xv*q0.w;
        s[4] += xv*q1.x;  s[5] += xv*q1.y;  s[6] += xv*q1.z;  s[7] += xv*q1.w;
        s[8] += xv*q2.x;  s[9] += xv*q2.y;  s[10]+= xv*q2.z;  s[11]+= xv*q2.w;
        s[12]+= xv*q3.x;  s[13]+= xv*q3.y;  s[14]+= xv*q3.z;  s[15]+= xv*q3.w;
    }
#pragma unroll
    for (int off = 32; off >= 1; off >>= 1) {
#pragma unroll
        for (int e = 0; e < E_NUM; ++e) s[e] += __shfl_xor(s[e], off);
    }
    if (lane == 0) {
#pragma unroll
        for (int e = 0; e < E_NUM; ++e) s[e] += bg[e];
        float b1v = -3e38f; int i1 = 0;
#pragma unroll
        for (int e = 0; e < E_NUM; ++e) { if (s[e] > b1v) { b1v = s[e]; i1 = e; } }
        float b2v = -3e38f; int i2 = 0;
#pragma unroll
        for (int e = 0; e < E_NUM; ++e) { if (e != i1 && s[e] > b2v) { b2v = s[e]; i2 = e; } }
        const float ex  = expf(b2v - b1v);
        const float inv = 1.f / (1.f + ex);
        e0[t] = i1; e1[t] = i2;
        w0[t] = inv; w1[t] = ex * inv;
    }
}

// ---------------- kernel 2: per-expert token lists ----------------
__global__ __launch_bounds__(64) void k_lists(const int* __restrict__ e0, const int* __restrict__ e1,
    const float* __restrict__ w0, const float* __restrict__ w1,
    int* __restrict__ lidx, float* __restrict__ lw,
    int* __restrict__ counts, float* __restrict__ sumw)
{
    const int e = blockIdx.x;
    const int lane = threadIdx.x;
    int cnt = 0; float sw = 0.f;
    for (int base = 0; base < T_TOK; base += 64) {
        const int t = base + lane;
        const bool m0 = (e0[t] == e);
        const bool m1 = (e1[t] == e);
        const bool m  = m0 | m1;
        const unsigned long long bal = __ballot(m);
        const int pos = cnt + __popcll(bal & ((1ull << lane) - 1ull));
        if (m) {
            const float w = m0 ? w0[t] : w1[t];
            lidx[e * T_TOK + pos] = t;
            lw[e * T_TOK + pos]   = w;
            sw += w;
        }
        cnt += __popcll(bal);
    }
#pragma unroll
    for (int off = 32; off >= 1; off >>= 1) sw += __shfl_xor(sw, off);
    if (lane == 0) { counts[e] = cnt; sumw[e] = sw; }
}

// ---------------- kernel 3: exclusive scan of 128-padded counts ----------------
__global__ void k_scan(const int* __restrict__ counts, int* __restrict__ xoff) {
    if (threadIdx.x == 0) {
        int o = 0;
        for (int e = 0; e < E_NUM; ++e) { xoff[e] = o; o += (counts[e] + CH_ROWS - 1) & ~(CH_ROWS - 1); }
    }
}

// ---------------- kernel 4: gather + f32->bf16 + chunk-swizzle into Xe ----------------
// Xe row layout: per 64-elem window, 16B chunk s holds logical chunk s ^ (row&7).
__global__ __launch_bounds__(256) void k_gather(const float* __restrict__ x,
    const int* __restrict__ lidx, const int* __restrict__ counts,
    const int* __restrict__ xoff, bf16_t* __restrict__ Xe)
{
    const int chunk = blockIdx.x >> 2;
    const int part  = blockIdx.x & 3;
    const int e = blockIdx.y;
    const int cnt = counts[e];
    const int start = chunk * CH_ROWS;
    if (chunk && start >= cnt) return;
    const int tid = threadIdx.x;
    const size_t rbase = (size_t)xoff[e] + start;

    for (int it = part * 16; it < part * 16 + 16; ++it) {
        const int task = it * 256 + tid;      // 16384 tasks: 128 rows x 128 chunks
        const int rl   = task >> 7;           // 0..127 local row
        const int sc   = task & 127;          // storage chunk within row
        const int row  = start + rl;
        bf16x8 v8 = {};
        if (row < cnt) {
            const int tok = lidx[e * T_TOK + row];
            const int l   = (sc & 7) ^ (rl & 7);
            const int k   = (sc >> 3) * 64 + l * 8;
            const float4 a = *(const float4*)(x + (size_t)tok * H_DIM + k);
            const float4 b = *(const float4*)(x + (size_t)tok * H_DIM + k + 4);
            v8[0]=(bf16_t)a.x; v8[1]=(bf16_t)a.y; v8[2]=(bf16_t)a.z; v8[3]=(bf16_t)a.w;
            v8[4]=(bf16_t)b.x; v8[5]=(bf16_t)b.y; v8[6]=(bf16_t)b.z; v8[7]=(bf16_t)b.w;
        }
        *(bf16x8*)(Xe + (rbase + rl) * H_DIM + sc * 8) = v8;
    }
}

// ---------------- kernel 5: expert GEMM, 2-phase pipelined ----------------
// grid: (F/64, CH_MAX, E). block 256 = 4 waves; wave tile 64 tok x 32 f; BK=64.
// Double-buffered: A via global_load_lds from pre-swizzled Xe (issued for t+1
// before computing t); B via T14 split (issue 16 HBM dwords early, cvt +
// ds_write to alt buffer after the MFMAs). One barrier per K-step.
__global__ __launch_bounds__(256, 3) void k_expert(
    const float* __restrict__ W1, const float* __restrict__ b1,
    const bf16_t* __restrict__ Xe, const float* __restrict__ lw,
    const int* __restrict__ counts, const int* __restrict__ xoff,
    float* __restrict__ gpart)
{
    const int ftile = blockIdx.x;   // 0..63
    const int chunk = blockIdx.y;   // 0..31
    const int e     = blockIdx.z;   // 0..15
    const int cnt   = counts[e];
    const int start = chunk * CH_ROWS;
    if (chunk && start >= cnt) return;

    __shared__ __align__(16) bf16_t Alds[2][CH_ROWS * 64];  // 2 x 16 KB
    __shared__ __align__(16) bf16_t Blds[2][64 * 72];       // 2 x 9 KB (padded rows)
    __shared__ float w_s[CH_ROWS];
    __shared__ float b1_s[64];
    __shared__ float gred[2][64];

    const int tid  = threadIdx.x;
    const int lane = tid & 63;
    const int wid  = tid >> 6;      // 4 waves
    const int wm   = wid & 1;       // M-group (64 rows)
    const int wn   = wid >> 1;      // N-group (32 f)
    const int lr   = lane & 15;
    const int lg   = lane >> 4;

    if (tid < CH_ROWS) {
        const int r = start + tid;
        w_s[tid] = (r < cnt) ? lw[e * T_TOK + r] : 0.f;
    } else if (tid < CH_ROWS + 64) {
        b1_s[tid - CH_ROWS] = b1[(size_t)e * F_DIM + ftile * 64 + (tid - CH_ROWS)];
    }

    f32x4 acc[4][2];
#pragma unroll
    for (int i = 0; i < 4; ++i)
#pragma unroll
        for (int j = 0; j < 2; ++j)
#pragma unroll
            for (int q = 0; q < 4; ++q) acc[i][j][q] = 0.f;

    const bf16_t* Asrc = Xe + ((size_t)xoff[e] + start) * H_DIM;
    const float*  W1p  = W1 + (size_t)e * H_DIM * F_DIM + (size_t)ftile * 64 + lane;

    // staging geometry
    const int arow = (wid * 4) * 8 + (lane >> 3);   // base row for p=0
    const int acol = lane & 7;                      // 16B chunk within 64-elem window

    float bv[16];

    // ---- prologue: stage k-step 0 into buffer 0 ----
    {
        const float* wp = W1p + (size_t)(wid * 16) * F_DIM;
#pragma unroll
        for (int j = 0; j < 16; ++j) bv[j] = wp[(size_t)j * F_DIM];
#pragma unroll
        for (int p = 0; p < 4; ++p) {
            const int seg = wid * 4 + p;
            const bf16_t* src = Asrc + (size_t)(seg * 8 + (lane >> 3)) * H_DIM + acol * 8;
            __builtin_amdgcn_global_load_lds(AS_GLOBAL(src),
                AS_LDS((char*)&Alds[0][0] + seg * 1024), 16, 0, 0);
        }
        bf16x8 pk0, pk1;
#pragma unroll
        for (int q = 0; q < 8; ++q) { pk0[q] = (bf16_t)bv[q]; pk1[q] = (bf16_t)bv[8 + q]; }
        bf16_t* bdst = &Blds[0][lane * 72 + wid * 16];
        *(bf16x8*)bdst       = pk0;
        *(bf16x8*)(bdst + 8) = pk1;
    }
    __syncthreads();

    int cur = 0;
    for (int t = 0; t < H_DIM / 64; ++t) {
        const int nxt = cur ^ 1;
        const bool more = (t + 1) < (H_DIM / 64);
        // ---- issue next tile's loads (fly under this tile's compute) ----
        if (more) {
            const int k0 = (t + 1) * 64;
            const float* wp = W1p + (size_t)(k0 + wid * 16) * F_DIM;
#pragma unroll
            for (int j = 0; j < 16; ++j) bv[j] = wp[(size_t)j * F_DIM];
#pragma unroll
            for (int p = 0; p < 4; ++p) {
                const int seg = wid * 4 + p;
                const bf16_t* src = Asrc + (size_t)(seg * 8 + (lane >> 3)) * H_DIM + k0 + acol * 8;
                __builtin_amdgcn_global_load_lds(AS_GLOBAL(src),
                    AS_LDS((char*)&Alds[nxt][0] + seg * 1024), 16, 0, 0);
            }
        }
        // ---- compute current tile ----
#pragma unroll
        for (int kh = 0; kh < 2; ++kh) {
            bf16x8 af[4], bfr[2];
#pragma unroll
            for (int mf = 0; mf < 4; ++mf) {
                const int r = wm * 64 + mf * 16 + lr;
                const int eoff = (kh * 32 + lg * 8) ^ ((r & 7) * 8);
                af[mf] = *(const bf16x8*)&Alds[cur][r * 64 + eoff];
            }
#pragma unroll
            for (int nf = 0; nf < 2; ++nf)
                bfr[nf] = *(const bf16x8*)&Blds[cur][(wn * 32 + nf * 16 + lr) * 72 + kh * 32 + lg * 8];
#pragma unroll
            for (int mf = 0; mf < 4; ++mf)
#pragma unroll
                for (int nf = 0; nf < 2; ++nf)
                    acc[mf][nf] = __builtin_amdgcn_mfma_f32_16x16x32_bf16(af[mf], bfr[nf], acc[mf][nf], 0, 0, 0);
        }
        // ---- write-late: B regs -> alt buffer (waits vmcnt for bv only) ----
        if (more) {
            bf16x8 pk0, pk1;
#pragma unroll
            for (int q = 0; q < 8; ++q) { pk0[q] = (bf16_t)bv[q]; pk1[q] = (bf16_t)bv[8 + q]; }
            bf16_t* bdst = &Blds[nxt][lane * 72 + wid * 16];
            *(bf16x8*)bdst       = pk0;
            *(bf16x8*)(bdst + 8) = pk1;
        }
        __syncthreads();   // drains A(t+1) gload_lds; orders B writes for t+1
        cur = nxt;
    }

    // ---- epilogue: exact gelu + weighted token-reduce ----
    float gcol[2] = {0.f, 0.f};
#pragma unroll
    for (int nf = 0; nf < 2; ++nf) {
        const float bb = b1_s[wn * 32 + nf * 16 + lr];
#pragma unroll
        for (int mf = 0; mf < 4; ++mf) {
#pragma unroll
            for (int i = 0; i < 4; ++i) {
                const int row = wm * 64 + mf * 16 + lg * 4 + i;  // C/D: col=lane&15, row=(lane>>4)*4+i
                const float h  = acc[mf][nf][i] + bb;
                const float gl = 0.5f * h * (1.f + erff(h * 0.70710678118654752f));
                gcol[nf] += w_s[row] * gl;
            }
        }
    }
#pragma unroll
    for (int nf = 0; nf < 2; ++nf) {
        gcol[nf] += __shfl_xor(gcol[nf], 16);
        gcol[nf] += __shfl_xor(gcol[nf], 32);
    }
    if (lane < 16) {
#pragma unroll
        for (int nf = 0; nf < 2; ++nf) gred[wm][wn * 32 + nf * 16 + lane] = gcol[nf];
    }
    __syncthreads();
    if (tid < 64) {
        const float sum = gred[0][tid] + gred[1][tid];
        gpart[(size_t)(e * CH_MAX + chunk) * F_DIM + ftile * 64 + tid] = sum;
    }
}

// ---------------- kernel 6: reduce chunk partials -> g[e][F] ----------------
__global__ __launch_bounds__(256) void k_redg(const float* __restrict__ gpart,
    const int* __restrict__ counts, float* __restrict__ g)
{
    const int e = blockIdx.y;
    const int f = blockIdx.x * 256 + threadIdx.x;
    const int nch = (counts[e] + CH_ROWS - 1) / CH_ROWS;
    float s = 0.f;
    for (int c = 0; c < nch; ++c)
        s += gpart[(size_t)(e * CH_MAX + c) * F_DIM + f];
    g[(size_t)e * F_DIM + f] = s;
}

// ---------------- kernel 7: W2 GEMV partials ----------------
__global__ __launch_bounds__(256) void k_out1(const float* __restrict__ g,
    const float* __restrict__ W2, float* __restrict__ p2)
{
    const int fc = blockIdx.x;
    const int e  = blockIdx.y;
    const int tid = threadIdx.x;
    __shared__ float gs[128];
    if (tid < 128) gs[tid] = g[(size_t)e * F_DIM + fc * 128 + tid];
    __syncthreads();
    const float* W2p = W2 + (size_t)e * F_DIM * H_DIM + (size_t)fc * 128 * H_DIM;
    float ax = 0.f, ay = 0.f, az = 0.f, aw = 0.f;
#pragma unroll 8
    for (int f = 0; f < 128; ++f) {
        const float gv = gs[f];
        const float4 wv = *(const float4*)(W2p + (size_t)f * H_DIM + tid * 4);
        ax += gv * wv.x; ay += gv * wv.y; az += gv * wv.z; aw += gv * wv.w;
    }
    float4 st; st.x = ax; st.y = ay; st.z = az; st.w = aw;
    *(float4*)(p2 + (size_t)(e * 32 + fc) * H_DIM + tid * 4) = st;
}

// ---------------- kernel 8: final reduce + bias + normalize ----------------
__global__ __launch_bounds__(256) void k_out2(const float* __restrict__ p2,
    const float* __restrict__ sumw, const float* __restrict__ b2, float* __restrict__ out)
{
    const int tid = threadIdx.x;
    const int hh  = tid & 31;
    const int seg = tid >> 5;
    const int h   = blockIdx.x * 32 + hh;
    float s = 0.f;
    for (int j = 0; j < 64; ++j)
        s += p2[(size_t)(seg * 64 + j) * H_DIM + h];
    __shared__ float red[8][33];
    red[seg][hh] = s;
    __syncthreads();
    if (tid < 32) {
        const int h2 = blockIdx.x * 32 + tid;
        float tot = 0.f;
#pragma unroll
        for (int q = 0; q < 8; ++q) tot += red[q][tid];
        float tw = 0.f, bias = 0.f;
#pragma unroll
        for (int e = 0; e < E_NUM; ++e) { tw += sumw[e]; bias += sumw[e] * b2[e * H_DIM + h2]; }
        out[h2] = (tot + bias) / tw;
    }
}

// ---------------- launch ----------------
extern "C" void kernel_launch(void* const* d_in, const int* in_sizes, int n_in,
                              void* d_out, int out_size, void* d_ws, size_t ws_size,
                              hipStream_t stream) {
    const float* x  = (const float*)d_in[0];
    const float* Wg = (const float*)d_in[1];
    const float* bg = (const float*)d_in[2];
    const float* W1 = (const float*)d_in[3];
    const float* b1 = (const float*)d_in[4];
    const float* W2 = (const float*)d_in[5];
    const float* b2 = (const float*)d_in[6];
    float* out = (float*)d_out;

    char* ws = (char*)d_ws;
    int*    e0     = (int*)(ws + WS_E0);
    int*    e1     = (int*)(ws + WS_E1);
    float*  w0     = (float*)(ws + WS_W0);
    float*  w1     = (float*)(ws + WS_W1);
    int*    counts = (int*)(ws + WS_COUNTS);
    float*  sumw   = (float*)(ws + WS_SUMW);
    int*    xoff   = (int*)(ws + WS_XOFF);
    int*    lidx   = (int*)(ws + WS_LIDX);
    float*  lw     = (float*)(ws + WS_LW);
    float*  gpart  = (float*)(ws + WS_GPART);
    float*  g      = (float*)(ws + WS_G);
    float*  p2     = (float*)(ws + WS_P2);   // aliases gpart (safe: gpart dead after k_redg)
    bf16_t* Xe     = (bf16_t*)(ws + WS_XE);

    k_route<<<T_TOK, 64, 0, stream>>>(x, Wg, bg, e0, e1, w0, w1);
    k_lists<<<E_NUM, 64, 0, stream>>>(e0, e1, w0, w1, lidx, lw, counts, sumw);
    k_scan<<<1, 64, 0, stream>>>(counts, xoff);
    k_gather<<<dim3(CH_MAX * 4, E_NUM), 256, 0, stream>>>(x, lidx, counts, xoff, Xe);
    k_expert<<<dim3(F_DIM / 64, CH_MAX, E_NUM), 256, 0, stream>>>(W1, b1, Xe, lw, counts, xoff, gpart);
    k_redg<<<dim3(F_DIM / 256, E_NUM), 256, 0, stream>>>(gpart, counts, g);
    k_out1<<<dim3(32, E_NUM), 256, 0, stream>>>(g, W2, p2);
    k_out2<<<32, 256, 0, stream>>>(p2, sumw, b2, out);
}

// Round 4
// 308.858 us; speedup vs baseline: 1.2426x; 1.0149x over previous
//
#include <hip/hip_runtime.h>
#include <hip/hip_bf16.h>
#include <math.h>

// ---------------- types ----------------
typedef __bf16 bf16_t;
typedef __bf16 bf16x4 __attribute__((ext_vector_type(4)));
typedef __bf16 bf16x8 __attribute__((ext_vector_type(8)));
typedef float  f32x4  __attribute__((ext_vector_type(4)));

#define T_TOK 4096
#define H_DIM 1024
#define E_NUM 16
#define F_DIM 4096
#define CH_ROWS 128   // tokens per chunk-block
#define CH_MAX  32    // max chunks per expert

// ---------------- workspace layout (bytes) ----------------
#define WS_E0     0            // int[4096]
#define WS_E1     16384        // int[4096]
#define WS_W0     32768        // float[4096]
#define WS_W1     49152        // float[4096]
#define WS_COUNTS 65536        // int[16]
#define WS_SUMW   65664        // float[16]
#define WS_XOFF   65792        // int[16]
#define WS_LIDX   131072       // int[16][4096]
#define WS_LW     393216       // float[16][4096]
#define WS_GPART  655360       // float[16][32][4096]  (8 MB)
#define WS_P2     655360       // float[512][1024] (2 MB) ALIASES gpart (dead after k_redg)
#define WS_G      9043968      // float[16][4096]
#define WS_XE     9306112      // bf16[10240][1024]  (20 MB), swizzle-permuted
// total: 30,277,632 bytes

#define AS_GLOBAL(p) ((const __attribute__((address_space(1))) void*)(p))
#define AS_LDS(p)    ((__attribute__((address_space(3))) void*)(p))

// ---------------- kernel 1: routing (scores + top2 + softmax) ----------------
__global__ __launch_bounds__(64) void k_route(const float* __restrict__ x,
    const float* __restrict__ Wg, const float* __restrict__ bg,
    int* __restrict__ e0, int* __restrict__ e1,
    float* __restrict__ w0, float* __restrict__ w1)
{
    const int t = blockIdx.x;
    const int lane = threadIdx.x;
    const float* xr = x + (size_t)t * H_DIM;

    float s[E_NUM];
#pragma unroll
    for (int e = 0; e < E_NUM; ++e) s[e] = 0.f;

#pragma unroll
    for (int i = 0; i < 16; ++i) {
        const int h = i * 64 + lane;
        const float xv = xr[h];
        const float4* wr = (const float4*)(Wg + (size_t)h * E_NUM);
        float4 q0 = wr[0], q1 = wr[1], q2 = wr[2], q3 = wr[3];
        s[0] += xv*q0.x;  s[1] += xv*q0.y;  s[2] += xv*q0.z;  s[3] += xv*q0.w;
        s[4] += xv*q1.x;  s[5] += xv*q1.y;  s[6] += xv*q1.z;  s[7] += xv*q1.w;
        s[8] += xv*q2.x;  s[9] += xv*q2.y;  s[10]+= xv*q2.z;  s[11]+= xv*q2.w;
        s[12]+= xv*q3.x;  s[13]+= xv*q3.y;  s[14]+= xv*q3.z;  s[15]+= xv*q3.w;
    }
#pragma unroll
    for (int off = 32; off >= 1; off >>= 1) {
#pragma unroll
        for (int e = 0; e < E_NUM; ++e) s[e] += __shfl_xor(s[e], off);
    }
    if (lane == 0) {
#pragma unroll
        for (int e = 0; e < E_NUM; ++e) s[e] += bg[e];
        float b1v = -3e38f; int i1 = 0;
#pragma unroll
        for (int e = 0; e < E_NUM; ++e) { if (s[e] > b1v) { b1v = s[e]; i1 = e; } }
        float b2v = -3e38f; int i2 = 0;
#pragma unroll
        for (int e = 0; e < E_NUM; ++e) { if (e != i1 && s[e] > b2v) { b2v = s[e]; i2 = e; } }
        const float ex  = expf(b2v - b1v);
        const float inv = 1.f / (1.f + ex);
        e0[t] = i1; e1[t] = i2;
        w0[t] = inv; w1[t] = ex * inv;
    }
}

// ---------------- kernel 2: per-expert token lists ----------------
__global__ __launch_bounds__(64) void k_lists(const int* __restrict__ e0, const int* __restrict__ e1,
    const float* __restrict__ w0, const float* __restrict__ w1,
    int* __restrict__ lidx, float* __restrict__ lw,
    int* __restrict__ counts, float* __restrict__ sumw)
{
    const int e = blockIdx.x;
    const int lane = threadIdx.x;
    int cnt = 0; float sw = 0.f;
    for (int base = 0; base < T_TOK; base += 64) {
        const int t = base + lane;
        const bool m0 = (e0[t] == e);
        const bool m1 = (e1[t] == e);
        const bool m  = m0 | m1;
        const unsigned long long bal = __ballot(m);
        const int pos = cnt + __popcll(bal & ((1ull << lane) - 1ull));
        if (m) {
            const float w = m0 ? w0[t] : w1[t];
            lidx[e * T_TOK + pos] = t;
            lw[e * T_TOK + pos]   = w;
            sw += w;
        }
        cnt += __popcll(bal);
    }
#pragma unroll
    for (int off = 32; off >= 1; off >>= 1) sw += __shfl_xor(sw, off);
    if (lane == 0) { counts[e] = cnt; sumw[e] = sw; }
}

// ---------------- kernel 3: exclusive scan of 128-padded counts ----------------
__global__ void k_scan(const int* __restrict__ counts, int* __restrict__ xoff) {
    if (threadIdx.x == 0) {
        int o = 0;
        for (int e = 0; e < E_NUM; ++e) { xoff[e] = o; o += (counts[e] + CH_ROWS - 1) & ~(CH_ROWS - 1); }
    }
}

// ---------------- kernel 4: gather + f32->bf16 + chunk-swizzle into Xe ----------------
// Xe row layout: per 64-elem window, 16B chunk s holds logical chunk s ^ (row&7).
__global__ __launch_bounds__(256) void k_gather(const float* __restrict__ x,
    const int* __restrict__ lidx, const int* __restrict__ counts,
    const int* __restrict__ xoff, bf16_t* __restrict__ Xe)
{
    const int chunk = blockIdx.x >> 2;
    const int part  = blockIdx.x & 3;
    const int e = blockIdx.y;
    const int cnt = counts[e];
    const int start = chunk * CH_ROWS;
    if (chunk && start >= cnt) return;
    const int tid = threadIdx.x;
    const size_t rbase = (size_t)xoff[e] + start;

    for (int it = part * 16; it < part * 16 + 16; ++it) {
        const int task = it * 256 + tid;      // 16384 tasks: 128 rows x 128 chunks
        const int rl   = task >> 7;           // 0..127 local row
        const int sc   = task & 127;          // storage chunk within row
        const int row  = start + rl;
        bf16x8 v8 = {};
        if (row < cnt) {
            const int tok = lidx[e * T_TOK + row];
            const int l   = (sc & 7) ^ (rl & 7);
            const int k   = (sc >> 3) * 64 + l * 8;
            const float4 a = *(const float4*)(x + (size_t)tok * H_DIM + k);
            const float4 b = *(const float4*)(x + (size_t)tok * H_DIM + k + 4);
            v8[0]=(bf16_t)a.x; v8[1]=(bf16_t)a.y; v8[2]=(bf16_t)a.z; v8[3]=(bf16_t)a.w;
            v8[4]=(bf16_t)b.x; v8[5]=(bf16_t)b.y; v8[6]=(bf16_t)b.z; v8[7]=(bf16_t)b.w;
        }
        *(bf16x8*)(Xe + (rbase + rl) * H_DIM + sc * 8) = v8;
    }
}

// ---------------- kernel 5: expert GEMM, deep-pipelined ----------------
// grid: (F/128, CH_MAX, E). block 256 = 4 waves (2M x 2N); wave tile 64x64; BK=64.
// A: global_load_lds dbuf from pre-swizzled Xe (issued at t for t+1).
// B: 2-deep register prefetch (issued at t for t+2), cvt+transpose ds_write late.
// Barriers: counted s_waitcnt vmcnt(32) + raw s_barrier (keeps B(t+2) in flight).
__global__ __launch_bounds__(256, 2) void k_expert(
    const float* __restrict__ W1, const float* __restrict__ b1,
    const bf16_t* __restrict__ Xe, const float* __restrict__ lw,
    const int* __restrict__ counts, const int* __restrict__ xoff,
    float* __restrict__ gpart)
{
    const int ftile = blockIdx.x;   // 0..31 (128 f each)
    const int chunk = blockIdx.y;   // 0..31
    const int e     = blockIdx.z;   // 0..15
    const int cnt   = counts[e];
    const int start = chunk * CH_ROWS;
    if (chunk && start >= cnt) return;

    __shared__ __align__(16) bf16_t Alds[2][CH_ROWS * 64];  // 2 x 16 KB, swizzled chunks
    __shared__ __align__(16) bf16_t Blds[2][128 * 72];      // 2 x 18 KB, [f][k] padded
    __shared__ float w_s[CH_ROWS];
    __shared__ float b1_s[128];
    __shared__ float gred[2][128];

    const int tid  = threadIdx.x;
    const int lane = tid & 63;
    const int wid  = tid >> 6;      // 4 waves
    const int wm   = wid & 1;       // M half (64 rows)
    const int wn   = wid >> 1;      // N half (64 f)
    const int lr   = lane & 15;
    const int lg   = lane >> 4;

    if (tid < CH_ROWS) {
        const int r = start + tid;
        w_s[tid] = (r < cnt) ? lw[e * T_TOK + r] : 0.f;
    }
    if (tid < 128) b1_s[tid] = b1[(size_t)e * F_DIM + ftile * 128 + tid];

    f32x4 acc[4][4];
#pragma unroll
    for (int i = 0; i < 4; ++i)
#pragma unroll
        for (int j = 0; j < 4; ++j)
#pragma unroll
            for (int q = 0; q < 4; ++q) acc[i][j][q] = 0.f;

    const bf16_t* Asrc = Xe + ((size_t)xoff[e] + start) * H_DIM;
    // B: thread owns column f (0..127) and k-half kh2 (0/1)
    const int bf_  = tid & 127;
    const int kh2  = tid >> 7;
    const float* W1p = W1 + (size_t)e * H_DIM * F_DIM + (size_t)ftile * 128 + bf_;

    float bvE[32], bvO[32];   // 2-deep B prefetch buffers (even/odd step parity)

#define ISSUE_A(T, BUFC) { \
    const int k0 = (T) * 64; \
    _Pragma("unroll") \
    for (int p = 0; p < 4; ++p) { \
        const int seg = wid * 4 + p; \
        const bf16_t* src = Asrc + (size_t)(seg * 8 + (lane >> 3)) * H_DIM + k0 + (lane & 7) * 8; \
        __builtin_amdgcn_global_load_lds(AS_GLOBAL(src), \
            AS_LDS((char*)&Alds[BUFC][0] + seg * 1024), 16, 0, 0); \
    } }

#define ISSUE_B(T, BV) { \
    const float* wp = W1p + (size_t)((T) * 64 + kh2 * 32) * F_DIM; \
    _Pragma("unroll") \
    for (int j = 0; j < 32; ++j) BV[j] = wp[(size_t)j * F_DIM]; }

#define WRITE_B(BUFC, BV) { \
    _Pragma("unroll") \
    for (int c = 0; c < 4; ++c) { \
        bf16x8 pk; \
        _Pragma("unroll") \
        for (int q = 0; q < 8; ++q) pk[q] = (bf16_t)BV[c * 8 + q]; \
        *(bf16x8*)&Blds[BUFC][bf_ * 72 + kh2 * 32 + c * 8] = pk; \
    } }

#define COMPUTE(BUFC) { \
    _Pragma("unroll") \
    for (int kh = 0; kh < 2; ++kh) { \
        bf16x8 af[4], bfr[4]; \
        _Pragma("unroll") \
        for (int mf = 0; mf < 4; ++mf) { \
            const int r = wm * 64 + mf * 16 + lr; \
            const int eoff = (kh * 32 + lg * 8) ^ ((r & 7) * 8); \
            af[mf] = *(const bf16x8*)&Alds[BUFC][r * 64 + eoff]; \
        } \
        _Pragma("unroll") \
        for (int nf = 0; nf < 4; ++nf) \
            bfr[nf] = *(const bf16x8*)&Blds[BUFC][(wn * 64 + nf * 16 + lr) * 72 + kh * 32 + lg * 8]; \
        _Pragma("unroll") \
        for (int mf = 0; mf < 4; ++mf) \
            _Pragma("unroll") \
            for (int nf = 0; nf < 4; ++nf) \
                acc[mf][nf] = __builtin_amdgcn_mfma_f32_16x16x32_bf16(af[mf], bfr[nf], acc[mf][nf], 0, 0, 0); \
    } }

#define SB0 __builtin_amdgcn_sched_barrier(0)

    // ---- prologue ----
    ISSUE_A(0, 0); SB0;
    ISSUE_B(0, bvE); SB0;
    ISSUE_B(1, bvO); SB0;
    WRITE_B(0, bvE);                 // compiler waits vmcnt for bvE (keeps bvO in flight)
    asm volatile("s_waitcnt vmcnt(32) lgkmcnt(0)" ::: "memory");  // A(0) drained, bvO flying
    SB0; __builtin_amdgcn_s_barrier(); SB0;

    // ---- main loop: unrolled x2 so buffer indices are literals ----
#define KSTEP(T, CUR, NXT, BVISS, BVWR) { \
    if ((T) < 15) { ISSUE_A((T) + 1, NXT); } SB0; \
    if ((T) < 14) { ISSUE_B((T) + 2, BVISS); } SB0; \
    COMPUTE(CUR); \
    if ((T) < 15) { WRITE_B(NXT, BVWR); } \
    if ((T) < 14) { \
        asm volatile("s_waitcnt vmcnt(32) lgkmcnt(0)" ::: "memory"); \
    } else { \
        asm volatile("s_waitcnt vmcnt(0) lgkmcnt(0)" ::: "memory"); \
    } \
    SB0; __builtin_amdgcn_s_barrier(); SB0; }

    for (int th = 0; th < 8; ++th) {
        const int t0 = th * 2;
        KSTEP(t0,     0, 1, bvE, bvO);
        KSTEP(t0 + 1, 1, 0, bvO, bvE);
    }

    // ---- epilogue: exact gelu + weighted token-reduce ----
    float gcol[4] = {0.f, 0.f, 0.f, 0.f};
#pragma unroll
    for (int nf = 0; nf < 4; ++nf) {
        const float bb = b1_s[wn * 64 + nf * 16 + lr];
#pragma unroll
        for (int mf = 0; mf < 4; ++mf) {
#pragma unroll
            for (int i = 0; i < 4; ++i) {
                const int row = wm * 64 + mf * 16 + lg * 4 + i;  // C/D: col=lane&15, row=(lane>>4)*4+i
                const float h  = acc[mf][nf][i] + bb;
                const float gl = 0.5f * h * (1.f + erff(h * 0.70710678118654752f));
                gcol[nf] += w_s[row] * gl;
            }
        }
    }
#pragma unroll
    for (int nf = 0; nf < 4; ++nf) {
        gcol[nf] += __shfl_xor(gcol[nf], 16);
        gcol[nf] += __shfl_xor(gcol[nf], 32);
    }
    if (lane < 16) {
#pragma unroll
        for (int nf = 0; nf < 4; ++nf) gred[wm][wn * 64 + nf * 16 + lane] = gcol[nf];
    }
    __syncthreads();
    if (tid < 128) {
        const float sum = gred[0][tid] + gred[1][tid];
        gpart[(size_t)(e * CH_MAX + chunk) * F_DIM + ftile * 128 + tid] = sum;
    }
#undef ISSUE_A
#undef ISSUE_B
#undef WRITE_B
#undef COMPUTE
#undef KSTEP
#undef SB0
}

// ---------------- kernel 6: reduce chunk partials -> g[e][F] ----------------
__global__ __launch_bounds__(256) void k_redg(const float* __restrict__ gpart,
    const int* __restrict__ counts, float* __restrict__ g)
{
    const int e = blockIdx.y;
    const int f = blockIdx.x * 256 + threadIdx.x;
    const int nch = (counts[e] + CH_ROWS - 1) / CH_ROWS;
    float s = 0.f;
    for (int c = 0; c < nch; ++c)
        s += gpart[(size_t)(e * CH_MAX + c) * F_DIM + f];
    g[(size_t)e * F_DIM + f] = s;
}

// ---------------- kernel 7: W2 GEMV partials ----------------
__global__ __launch_bounds__(256) void k_out1(const float* __restrict__ g,
    const float* __restrict__ W2, float* __restrict__ p2)
{
    const int fc = blockIdx.x;
    const int e  = blockIdx.y;
    const int tid = threadIdx.x;
    __shared__ float gs[128];
    if (tid < 128) gs[tid] = g[(size_t)e * F_DIM + fc * 128 + tid];
    __syncthreads();
    const float* W2p = W2 + (size_t)e * F_DIM * H_DIM + (size_t)fc * 128 * H_DIM;
    float ax = 0.f, ay = 0.f, az = 0.f, aw = 0.f;
#pragma unroll 8
    for (int f = 0; f < 128; ++f) {
        const float gv = gs[f];
        const float4 wv = *(const float4*)(W2p + (size_t)f * H_DIM + tid * 4);
        ax += gv * wv.x; ay += gv * wv.y; az += gv * wv.z; aw += gv * wv.w;
    }
    float4 st; st.x = ax; st.y = ay; st.z = az; st.w = aw;
    *(float4*)(p2 + (size_t)(e * 32 + fc) * H_DIM + tid * 4) = st;
}

// ---------------- kernel 8: final reduce + bias + normalize ----------------
__global__ __launch_bounds__(256) void k_out2(const float* __restrict__ p2,
    const float* __restrict__ sumw, const float* __restrict__ b2, float* __restrict__ out)
{
    const int tid = threadIdx.x;
    const int hh  = tid & 31;
    const int seg = tid >> 5;
    const int h   = blockIdx.x * 32 + hh;
    float s = 0.f;
    for (int j = 0; j < 64; ++j)
        s += p2[(size_t)(seg * 64 + j) * H_DIM + h];
    __shared__ float red[8][33];
    red[seg][hh] = s;
    __syncthreads();
    if (tid < 32) {
        const int h2 = blockIdx.x * 32 + tid;
        float tot = 0.f;
#pragma unroll
        for (int q = 0; q < 8; ++q) tot += red[q][tid];
        float tw = 0.f, bias = 0.f;
#pragma unroll
        for (int e = 0; e < E_NUM; ++e) { tw += sumw[e]; bias += sumw[e] * b2[e * H_DIM + h2]; }
        out[h2] = (tot + bias) / tw;
    }
}

// ---------------- launch ----------------
extern "C" void kernel_launch(void* const* d_in, const int* in_sizes, int n_in,
                              void* d_out, int out_size, void* d_ws, size_t ws_size,
                              hipStream_t stream) {
    const float* x  = (const float*)d_in[0];
    const float* Wg = (const float*)d_in[1];
    const float* bg = (const float*)d_in[2];
    const float* W1 = (const float*)d_in[3];
    const float* b1 = (const float*)d_in[4];
    const float* W2 = (const float*)d_in[5];
    const float* b2 = (const float*)d_in[6];
    float* out = (float*)d_out;

    char* ws = (char*)d_ws;
    int*    e0     = (int*)(ws + WS_E0);
    int*    e1     = (int*)(ws + WS_E1);
    float*  w0     = (float*)(ws + WS_W0);
    float*  w1     = (float*)(ws + WS_W1);
    int*    counts = (int*)(ws + WS_COUNTS);
    float*  sumw   = (float*)(ws + WS_SUMW);
    int*    xoff   = (int*)(ws + WS_XOFF);
    int*    lidx   = (int*)(ws + WS_LIDX);
    float*  lw     = (float*)(ws + WS_LW);
    float*  gpart  = (float*)(ws + WS_GPART);
    float*  g      = (float*)(ws + WS_G);
    float*  p2     = (float*)(ws + WS_P2);   // aliases gpart (safe: gpart dead after k_redg)
    bf16_t* Xe     = (bf16_t*)(ws + WS_XE);

    k_route<<<T_TOK, 64, 0, stream>>>(x, Wg, bg, e0, e1, w0, w1);
    k_lists<<<E_NUM, 64, 0, stream>>>(e0, e1, w0, w1, lidx, lw, counts, sumw);
    k_scan<<<1, 64, 0, stream>>>(counts, xoff);
    k_gather<<<dim3(CH_MAX * 4, E_NUM), 256, 0, stream>>>(x, lidx, counts, xoff, Xe);
    k_expert<<<dim3(F_DIM / 128, CH_MAX, E_NUM), 256, 0, stream>>>(W1, b1, Xe, lw, counts, xoff, gpart);
    k_redg<<<dim3(F_DIM / 256, E_NUM), 256, 0, stream>>>(gpart, counts, g);
    k_out1<<<dim3(32, E_NUM), 256, 0, stream>>>(g, W2, p2);
    k_out2<<<32, 256, 0, stream>>>(p2, sumw, b2, out);
}